// Round 1
// baseline (238.993 us; speedup 1.0000x reference)
//
#include <hip/hip_runtime.h>

// PositionalEncoding: out[b,s,i] = x[b,s,i] + pe[s,i]
//   pe[s,i] = sin(s / 10000^((i/2)/D))  if i even
//             cos(s / 10000^((i/2)/D))  if i odd
// B=8, S=4096, D=1024, fp32. Memory-bound: 268 MB traffic -> ~43 us floor.
//
// Strategy: one thread per (s, i..i+3) float4; compute the 4 PE values once
// (two k's -> two angles -> sincos each), then loop b=0..7 doing coalesced
// float4 load+add+store. Amortizes transcendentals 8x over the batch dim.

#define PE_B 8
#define PE_S 4096
#define PE_D 1024

__global__ __launch_bounds__(256) void pe_add_kernel(
    const float* __restrict__ x, float* __restrict__ out) {
    const int tid = blockIdx.x * blockDim.x + threadIdx.x;   // 0 .. S*D/4-1
    const int i4  = tid & (PE_D / 4 - 1);                    // float4 index in row
    const int s   = tid >> 8;                                // D/4 = 256
    const int i   = i4 * 4;

    const float pos = (float)s;
    // inv_freq = 10000^(-k/D) = exp2(k * -log2(10000)/D)
    const float c  = -13.287712379549449f / (float)PE_D;
    const float k0 = (float)(i >> 1);
    const float a0 = pos * exp2f(k0 * c);
    const float a1 = pos * exp2f((k0 + 1.0f) * c);

    float s0, c0, s1, c1;
    sincosf(a0, &s0, &c0);
    sincosf(a1, &s1, &c1);
    // i even->sin, i+1 odd->cos (same k), i+2 even->sin, i+3 odd->cos (k+1)
    const float4 pe = make_float4(s0, c0, s1, c1);

    const size_t off    = (size_t)tid * 4;
    const size_t stride = (size_t)PE_S * PE_D;

#pragma unroll
    for (int b = 0; b < PE_B; ++b) {
        const float4 v = *(const float4*)(x + b * stride + off);
        float4 r;
        r.x = v.x + pe.x;
        r.y = v.y + pe.y;
        r.z = v.z + pe.z;
        r.w = v.w + pe.w;
        *(float4*)(out + b * stride + off) = r;
    }
}

extern "C" void kernel_launch(void* const* d_in, const int* in_sizes, int n_in,
                              void* d_out, int out_size, void* d_ws, size_t ws_size,
                              hipStream_t stream) {
    const float* x = (const float*)d_in[0];
    float* out = (float*)d_out;
    // S*D/4 = 1,048,576 threads -> 4096 blocks of 256
    const int threads = PE_S * PE_D / 4;
    pe_add_kernel<<<threads / 256, 256, 0, stream>>>(x, out);
}